// Round 7
// baseline (629.085 us; speedup 1.0000x reference)
//
#include <hip/hip_runtime.h>
#include <hip/hip_bf16.h>

#define T_TOK 1024
#define DIM   1024
#define NE    8
#define NH    4096
#define MT    320   // per-expert m-tile: covers cnte=256+3.2sigma in ONE tile

typedef _Float16 f16;
typedef _Float16 f16x4 __attribute__((ext_vector_type(4)));
typedef _Float16 f16x8 __attribute__((ext_vector_type(8)));
typedef float    f32x4 __attribute__((ext_vector_type(4)));

// ---------------- workspace layout (bytes) ----------------
#define WS_CNT      0                        // 8 int
#define WS_EPOS     2048                     // 2048 int (token -> e*1024+pos)
#define WS_TOK      16384                    // 8*1024 int
#define WS_WGT      65536                    // 8*1024 float
#define WS_XG       131072                   // 2048*1024 f16 = 4 MiB (compact scaled rows)
#define WS_A        (WS_XG + 2048*1024*2)    // 2048*4096 f16 = 16 MiB
#define WS_Y        (WS_A + 2048*4096*2)     // 2048*1024 float = 8 MiB
#define WS_NEEDED   (WS_Y + 2048*1024*4)     // ~29.5 MB

__global__ void zero_cnt_kernel(int* cnt) { if (threadIdx.x < 8) cnt[threadIdx.x] = 0; }

// ---------------- gate: one wave per token ----------------
__global__ void gate_kernel(const float* __restrict__ X, const float* __restrict__ Wg,
                            const float* __restrict__ bg, int* cnt, int* tok,
                            float* wgt, int* epos) {
    int lane = threadIdx.x & 63;
    int wv   = threadIdx.x >> 6;
    int t    = blockIdx.x * 4 + wv;
    if (t >= T_TOK) return;

    float acc[8];
#pragma unroll
    for (int e = 0; e < 8; ++e) acc[e] = 0.f;
    const float* xrow = X + (size_t)t * DIM;
    for (int d = lane; d < DIM; d += 64) {
        float xv = xrow[d];
        const float* wr = Wg + (size_t)d * NE;
#pragma unroll
        for (int e = 0; e < 8; ++e) acc[e] += xv * wr[e];
    }
#pragma unroll
    for (int off = 32; off > 0; off >>= 1) {
#pragma unroll
        for (int e = 0; e < 8; ++e) acc[e] += __shfl_down(acc[e], off);
    }
    if (lane == 0) {
        float lg[8];
#pragma unroll
        for (int e = 0; e < 8; ++e) lg[e] = acc[e] + bg[e];
        int i0 = 0;
#pragma unroll
        for (int e = 1; e < 8; ++e) if (lg[e] > lg[i0]) i0 = e;
        int i1 = (i0 == 0) ? 1 : 0;
#pragma unroll
        for (int e = 0; e < 8; ++e) if (e != i0 && lg[e] > lg[i1]) i1 = e;
        float w0 = 1.f / (1.f + __expf(lg[i1] - lg[i0]));
        float w1 = 1.f - w0;
        int p0 = atomicAdd(&cnt[i0], 1);
        tok[i0 * 1024 + p0] = t;  wgt[i0 * 1024 + p0] = w0;
        epos[2 * t + 0] = i0 * 1024 + p0;
        int p1 = atomicAdd(&cnt[i1], 1);
        tok[i1 * 1024 + p1] = t;  wgt[i1 * 1024 + p1] = w1;
        epos[2 * t + 1] = i1 * 1024 + p1;
    }
}

// inline prefix over the 8 expert counts (uniform scalar loads, L2-hit)
__device__ __forceinline__ void load_counts(const int* __restrict__ cnt, int e,
                                            int& cnte, int& rs) {
    int c[8];
#pragma unroll
    for (int i = 0; i < 8; ++i) c[i] = cnt[i];
    cnte = c[e];
    rs = 0;
#pragma unroll
    for (int i = 0; i < 8; ++i) rs += (i < e) ? c[i] : 0;
}

// ---------------- pregather: Xg[rs+p] = fp16( X[tok] * w ) ----------------
// Hoists gather+scale+convert OUT of ffn1's 64x-replicated n-tile loop.
// grid (8, MT), 256 thr; p-loop covers the cnte>MT tail.
__global__ void pregather_kernel(const float* __restrict__ X, const int* __restrict__ cnt,
                                 const int* __restrict__ tok, const float* __restrict__ wgt,
                                 f16* __restrict__ Xg) {
    int e = blockIdx.x;
    int cnte, rs;
    load_counts(cnt, e, cnte, rs);
    for (int p = blockIdx.y; p < cnte; p += MT) {
        int t   = tok[e * 1024 + p];
        float w = wgt[e * 1024 + p];
        int d   = threadIdx.x * 4;
        float4 xv = *(const float4*)(X + (size_t)t * DIM + d);
        f16x4 hv;
        hv[0] = (f16)(xv.x * w); hv[1] = (f16)(xv.y * w);
        hv[2] = (f16)(xv.z * w); hv[3] = (f16)(xv.w * w);
        *(f16x4*)(Xg + (size_t)(rs + p) * DIM + d) = hv;
    }
}

// ---------------- ffn1: A = silu(Xg @ W1e) * (Xg @ W3e), fp16 out ----------------
// tile: M=320 compact rows, N=64 cols of H, K-step 32.
// 512 thr = 8 waves (4m x 2n); each wave owns 80 rows = 5 x 16-row fragments.
__global__ __launch_bounds__(512)
void ffn1_kernel(const f16* __restrict__ Xg, const float* __restrict__ W1,
                 const float* __restrict__ W3, const int* __restrict__ cnt,
                 f16* __restrict__ A) {
    int e = blockIdx.z;
    int cnte, rs;
    load_counts(cnt, e, cnte, rs);
    int mt = blockIdx.y;
    if (mt * MT >= cnte) return;   // safety tile only active if cnte > 320
    int n0 = blockIdx.x * 64;
    int tid = threadIdx.x;

    __shared__ f16 Xs[MT][40];    // 80B row stride: 16B-aligned b128, conflict-light
    __shared__ f16 W1s[64][40];
    __shared__ f16 W3s[64][40];

    const float* W1e = W1 + (size_t)e * DIM * NH;
    const float* W3e = W3 + (size_t)e * DIM * NH;

    int lane = tid & 63;
    int wv   = tid >> 6;      // 0..7
    int mw   = wv >> 1;       // 0..3 -> rows mw*80
    int nw   = wv & 1;        // 0..1 -> cols nw*32

    f32x4 acc1[5][2] = {};
    f32x4 acc3[5][2] = {};

    int rowbase = rs + mt * MT;

    for (int k0 = 0; k0 < DIM; k0 += 32) {
        __syncthreads();
        // --- stage Xg tile (already scaled fp16): 320 rows x 32 halfs; 1280 16B chunks ---
        for (int i = tid; i < 4 * MT; i += 512) {
            int r   = i >> 2;
            int col = (i & 3) * 8;
            int arow = rowbase + r;
            if (arow > 2047) arow = 2047;  // clamp: reads valid data, result discarded
            *(float4*)&Xs[r][col] =
                *(const float4*)(Xg + (size_t)arow * DIM + k0 + col);
        }
        // --- stage W1/W3 tiles transposed: lane=col, wave=k-group of 4 ---
        {
            int kb = k0 + wv * 4;
            f16x4 h1v, h3v;
#pragma unroll
            for (int i = 0; i < 4; ++i) {
                h1v[i] = (f16)W1e[(size_t)(kb + i) * NH + n0 + lane];
                h3v[i] = (f16)W3e[(size_t)(kb + i) * NH + n0 + lane];
            }
            *(f16x4*)&W1s[lane][wv * 4] = h1v;
            *(f16x4*)&W3s[lane][wv * 4] = h3v;
        }
        __syncthreads();
        // --- fragments + MFMA ---
        int kg = (lane >> 4) * 8;
        f16x8 a[5];
#pragma unroll
        for (int mf = 0; mf < 5; ++mf)
            a[mf] = *(const f16x8*)&Xs[mw * 80 + mf * 16 + (lane & 15)][kg];
#pragma unroll
        for (int nf = 0; nf < 2; ++nf) {
            f16x8 b1 = *(const f16x8*)&W1s[nw * 32 + nf * 16 + (lane & 15)][kg];
            f16x8 b3 = *(const f16x8*)&W3s[nw * 32 + nf * 16 + (lane & 15)][kg];
#pragma unroll
            for (int mf = 0; mf < 5; ++mf) {
                acc1[mf][nf] = __builtin_amdgcn_mfma_f32_16x16x32_f16(a[mf], b1, acc1[mf][nf], 0, 0, 0);
                acc3[mf][nf] = __builtin_amdgcn_mfma_f32_16x16x32_f16(a[mf], b3, acc3[mf][nf], 0, 0, 0);
            }
        }
    }
    // --- epilogue: silu(h1)*h3 -> fp16 A (compact rows), guarded ---
#pragma unroll
    for (int mf = 0; mf < 5; ++mf)
#pragma unroll
        for (int nf = 0; nf < 2; ++nf)
#pragma unroll
            for (int r = 0; r < 4; ++r) {
                int j = mt * MT + mw * 80 + mf * 16 + (lane >> 4) * 4 + r;
                if (j < cnte) {
                    float h1 = acc1[mf][nf][r];
                    float h3 = acc3[mf][nf][r];
                    float av = (h1 / (1.f + __expf(-h1))) * h3;
                    A[(size_t)(rs + j) * NH + n0 + nw * 32 + nf * 16 + (lane & 15)] = (f16)av;
                }
            }
}

// ---------------- ffn2: Y = A @ W2e, fp32 out ----------------
// tile: M=320, N=64, K-step 32. 512 thr = 8 waves (4m x 2n), 5 frags/wave.
__global__ __launch_bounds__(512)
void ffn2_kernel(const f16* __restrict__ A, const float* __restrict__ W2,
                 const int* __restrict__ cnt, float* __restrict__ Y) {
    int e = blockIdx.z;
    int cnte, rs;
    load_counts(cnt, e, cnte, rs);
    int mt = blockIdx.y;
    if (mt * MT >= cnte) return;
    int n0 = blockIdx.x * 64;
    int tid = threadIdx.x;

    __shared__ f16 As[MT][40];
    __shared__ f16 W2s[64][40];

    int lane = tid & 63;
    int wv   = tid >> 6;      // 0..7
    int mw   = wv >> 1;       // 0..3 -> rows mw*80
    int nw   = wv & 1;        // 0..1 -> cols nw*32

    f32x4 acc[5][2] = {};

    const float* W2e = W2 + (size_t)e * NH * DIM;
    int rowbase = rs + mt * MT;

    for (int k0 = 0; k0 < NH; k0 += 32) {
        __syncthreads();
        // --- stage A tile (already fp16): 320 rows x 32 halfs; 640 16-half chunks ---
        for (int i = tid; i < 2 * MT; i += 512) {
            int r   = i >> 1;
            int col = (i & 1) * 16;
            int arow = rowbase + r;
            if (arow > 2047) arow = 2047;  // clamp: reads valid (written) data, result discarded
            float4 v0 = *(const float4*)(A + (size_t)arow * NH + k0 + col);
            float4 v1 = *(const float4*)(A + (size_t)arow * NH + k0 + col + 8);
            *(float4*)&As[r][col]     = v0;
            *(float4*)&As[r][col + 8] = v1;
        }
        // --- stage W2 transposed: lane=col, wave=k-group of 4 ---
        {
            int kb = k0 + wv * 4;
            f16x4 hv;
#pragma unroll
            for (int i = 0; i < 4; ++i)
                hv[i] = (f16)W2e[(size_t)(kb + i) * DIM + n0 + lane];
            *(f16x4*)&W2s[lane][wv * 4] = hv;
        }
        __syncthreads();
        int kg = (lane >> 4) * 8;
        f16x8 a[5];
#pragma unroll
        for (int mf = 0; mf < 5; ++mf)
            a[mf] = *(const f16x8*)&As[mw * 80 + mf * 16 + (lane & 15)][kg];
#pragma unroll
        for (int nf = 0; nf < 2; ++nf) {
            f16x8 b = *(const f16x8*)&W2s[nw * 32 + nf * 16 + (lane & 15)][kg];
#pragma unroll
            for (int mf = 0; mf < 5; ++mf)
                acc[mf][nf] = __builtin_amdgcn_mfma_f32_16x16x32_f16(a[mf], b, acc[mf][nf], 0, 0, 0);
        }
    }
#pragma unroll
    for (int mf = 0; mf < 5; ++mf)
#pragma unroll
        for (int nf = 0; nf < 2; ++nf)
#pragma unroll
            for (int r = 0; r < 4; ++r) {
                int j = mt * MT + mw * 80 + mf * 16 + (lane >> 4) * 4 + r;
                if (j < cnte) {
                    Y[(size_t)(rs + j) * DIM + n0 + nw * 32 + nf * 16 + (lane & 15)] =
                        acc[mf][nf][r];
                }
            }
}

// ---------------- combine: out = X + Y[slot0] + Y[slot1] ----------------
__global__ void combine_kernel(const float* __restrict__ X, const float* __restrict__ Y,
                               const int* __restrict__ epos, const int* __restrict__ cnt,
                               float* __restrict__ out) {
    int t  = blockIdx.x;
    int c[8];
#pragma unroll
    for (int i = 0; i < 8; ++i) c[i] = cnt[i];
    int pre[8];
    {
        int s = 0;
#pragma unroll
        for (int i = 0; i < 8; ++i) { pre[i] = s; s += c[i]; }
    }
    int c0 = epos[2 * t + 0];
    int c1 = epos[2 * t + 1];
    int r0 = pre[c0 >> 10] + (c0 & 1023);
    int r1 = pre[c1 >> 10] + (c1 & 1023);
    int d  = threadIdx.x * 4;
    float4 xv = *(const float4*)(X + (size_t)t * DIM + d);
    float4 y0 = *(const float4*)(Y + (size_t)r0 * DIM + d);
    float4 y1 = *(const float4*)(Y + (size_t)r1 * DIM + d);
    float4 o;
    o.x = xv.x + y0.x + y1.x;
    o.y = xv.y + y0.y + y1.y;
    o.z = xv.z + y0.z + y1.z;
    o.w = xv.w + y0.w + y1.w;
    *(float4*)(out + (size_t)t * DIM + d) = o;
}

extern "C" void kernel_launch(void* const* d_in, const int* in_sizes, int n_in,
                              void* d_out, int out_size, void* d_ws, size_t ws_size,
                              hipStream_t stream) {
    // Workspace-size guard: never write OOB (a fault would kill the container
    // and be indistinguishable from infra failure).
    if (ws_size < (size_t)WS_NEEDED) return;

    const float* X  = (const float*)d_in[0];
    const float* Wg = (const float*)d_in[1];
    const float* bg = (const float*)d_in[2];
    const float* W1 = (const float*)d_in[3];
    const float* W2 = (const float*)d_in[4];
    const float* W3 = (const float*)d_in[5];
    float* out = (float*)d_out;

    char* ws = (char*)d_ws;
    int*   cnt  = (int*)(ws + WS_CNT);
    int*   epos = (int*)(ws + WS_EPOS);
    int*   tok  = (int*)(ws + WS_TOK);
    float* wgt  = (float*)(ws + WS_WGT);
    f16*   Xg   = (f16*)(ws + WS_XG);
    f16*   A    = (f16*)(ws + WS_A);
    float* Y    = (float*)(ws + WS_Y);

    zero_cnt_kernel<<<1, 64, 0, stream>>>(cnt);
    gate_kernel<<<T_TOK / 4, 256, 0, stream>>>(X, Wg, bg, cnt, tok, wgt, epos);
    pregather_kernel<<<dim3(8, MT), 256, 0, stream>>>(X, cnt, tok, wgt, Xg);
    // y=2: second m-tile is a safety net, early-exits unless cnte > 320 (P ~ 5e-4)
    ffn1_kernel<<<dim3(64, 2, 8), 512, 0, stream>>>(Xg, W1, W3, cnt, A);
    ffn2_kernel<<<dim3(16, 2, 8), 512, 0, stream>>>(A, W2, cnt, Y);
    combine_kernel<<<T_TOK, 256, 0, stream>>>(X, Y, epos, cnt, out);
}